// Round 15
// baseline (1708.131 us; speedup 1.0000x reference)
//
#include <hip/hip_runtime.h>

typedef unsigned short u16;
typedef unsigned long long u64;
typedef __attribute__((ext_vector_type(8))) short short8;
typedef __attribute__((ext_vector_type(4))) float f32x4;
typedef __attribute__((ext_vector_type(4))) unsigned int u32x4;

#define N_NODES 40000
#define N_EDGES 640000

// ---------- bf16 helpers (RNE) ----------
__device__ __forceinline__ u16 f2bf(float f) {
  unsigned int u = __builtin_bit_cast(unsigned int, f);
  u += 0x7FFFu + ((u >> 16) & 1u);
  return (u16)(u >> 16);
}
__device__ __forceinline__ float bf2f(u16 h) {
  unsigned int u = ((unsigned int)h) << 16;
  return __builtin_bit_cast(float, u);
}
// relu on 8 packed bf16 (sign-mask trick)
__device__ __forceinline__ short8 relu8(short8 s) {
  u32x4 w = __builtin_bit_cast(u32x4, s);
#pragma unroll
  for (int j = 0; j < 4; ++j) {
    unsigned int t = (w[j] >> 15) & 0x10001u;
    w[j] &= ~(t * 0xFFFFu);
  }
  return __builtin_bit_cast(short8, w);
}
// packed bf16 atomic add (gfx950 global_atomic_pk_add_bf16)
__device__ __forceinline__ void pk_atomic_add_bf16(u16* p, float c0, float c1) {
  unsigned int pk = (unsigned int)f2bf(c0) | ((unsigned int)f2bf(c1) << 16);
  asm volatile("global_atomic_pk_add_bf16 %0, %1, off" :: "v"(p), "v"(pk) : "memory");
}

// ---------- prep: W1/W2 f32 -> bf16, permuted into MFMA B-fragment order ----
// B frag for (ntile,ks): lane l holds B[k=ks*32+(l>>4)*8+j][n=ntile*16+(l&15)]
__global__ void prep_weights(const float* __restrict__ W1,
                             const float* __restrict__ W2,
                             u16* __restrict__ w1t, u16* __restrict__ w2t) {
  int gid = blockIdx.x * 256 + threadIdx.x;
  if (gid < 3 * 16 * 8 * 64) {            // W1: 3 layers x 16 ntiles x 8 ks x 64 lanes
    int l = gid >> 13;
    int rem = gid & 8191;
    int ntg = rem >> 9;
    int ks = (rem >> 6) & 7;
    int lane = rem & 63;
    int n = ntg * 16 + (lane & 15);
    int k0 = ks * 32 + (lane >> 4) * 8;
    const float* s = W1 + l * 65536 + n * 256 + k0;
    u16* d = w1t + (size_t)gid * 8;
#pragma unroll
    for (int j = 0; j < 8; ++j) d[j] = f2bf(s[j]);
  } else if (gid < 3 * 16 * 8 * 64 + 3 * 8 * 8 * 64) {  // W2: 8 ntiles
    int g = gid - 3 * 16 * 8 * 64;
    int l = g >> 12;
    int rem = g & 4095;
    int ntg = rem >> 9;
    int ks = (rem >> 6) & 7;
    int lane = rem & 63;
    int n = ntg * 16 + (lane & 15);
    int k0 = ks * 32 + (lane >> 4) * 8;
    const float* s = W2 + l * 32768 + n * 256 + k0;
    u16* d = w2t + (size_t)g * 8;
#pragma unroll
    for (int j = 0; j < 8; ++j) d[j] = f2bf(s[j]);
  }
}

// ---------- f32 -> bf16, vectorized x8 (initial h only) ----------
__global__ void cvt_vec(const float* __restrict__ in, u16* __restrict__ out,
                        int n8) {
  int i = blockIdx.x * 256 + threadIdx.x;
  if (i >= n8) return;
  const float4* p = reinterpret_cast<const float4*>(in) + (size_t)i * 2;
  float4 a = p[0], b = p[1];
  short8 v;
  v[0] = (short)f2bf(a.x); v[1] = (short)f2bf(a.y);
  v[2] = (short)f2bf(a.z); v[3] = (short)f2bf(a.w);
  v[4] = (short)f2bf(b.x); v[5] = (short)f2bf(b.y);
  v[6] = (short)f2bf(b.z); v[7] = (short)f2bf(b.w);
  *reinterpret_cast<short8*>(out + (size_t)i * 8) = v;
}

// ---------- counting sort of edges by dst ----------
__global__ void hist_dst(const int* __restrict__ dst, int* __restrict__ cnt) {
  int e = blockIdx.x * 256 + threadIdx.x;
  if (e < N_EDGES) atomicAdd(&cnt[dst[e]], 1);
}

__global__ void scan_hist(const int* __restrict__ cnt, int* __restrict__ cursor) {
  __shared__ int ls[1024];
  const int tid = threadIdx.x;  // 1024 threads, 40 nodes each
  const int b = tid * 40;
  const int lim = (b < N_NODES) ? ((N_NODES - b < 40) ? (N_NODES - b) : 40) : 0;
  int s = 0;
  for (int j = 0; j < lim; ++j) s += cnt[b + j];
  ls[tid] = s;
  __syncthreads();
  for (int off = 1; off < 1024; off <<= 1) {
    int v = (tid >= off) ? ls[tid - off] : 0;
    __syncthreads();
    ls[tid] += v;
    __syncthreads();
  }
  int run = (tid == 0) ? 0 : ls[tid - 1];
  for (int j = 0; j < lim; ++j) {
    cursor[b + j] = run;
    run += cnt[b + j];
  }
}

__global__ void rank_edges(const int* __restrict__ src, const int* __restrict__ dst,
                           int* __restrict__ cursor, int* __restrict__ srcS,
                           int* __restrict__ dstS, int* __restrict__ rank) {
  int e = blockIdx.x * 256 + threadIdx.x;
  if (e >= N_EDGES) return;
  int d = dst[e];
  int r = atomicAdd(&cursor[d], 1);
  rank[e] = r;
  srcS[r] = src[e];
  dstS[r] = d;
}

// ---------- permute e into sorted slot order, f32 -> bf16 (raw, no relu) ----
__global__ void permute_e(const float* __restrict__ e, const int* __restrict__ rank,
                          u16* __restrict__ ebfS) {
  int t = blockIdx.x * 256 + threadIdx.x;
  int row = t >> 2;
  int part = t & 3;  // 32-float chunk of the row
  if (row >= N_EDGES) return;
  const float4* p = reinterpret_cast<const float4*>(e + (size_t)row * 128 + part * 32);
  u16* dp = ebfS + (size_t)rank[row] * 128 + part * 32;
#pragma unroll
  for (int j = 0; j < 4; ++j) {
    float4 a = p[j * 2], b = p[j * 2 + 1];
    short8 v;
    v[0] = (short)f2bf(a.x); v[1] = (short)f2bf(a.y);
    v[2] = (short)f2bf(a.z); v[3] = (short)f2bf(a.w);
    v[4] = (short)f2bf(b.x); v[5] = (short)f2bf(b.y);
    v[6] = (short)f2bf(b.z); v[7] = (short)f2bf(b.w);
    *(short8*)(dp + j * 8) = v;
  }
}

// ---------- ladder building blocks ----------
#define LOAD_B4(SET, KS) { _Pragma("unroll") \
  for (int nt = 0; nt < 4; ++nt) \
    SET[nt] = *(const short8*)(wbase + ((nt * 8 + (KS)) * 64 + lane) * 8); }
// A read from swizzled LDS: logical chunk lk lives at physical chunk
// lk ^ (row&3); row&3 == lrow&3 (mt*16 multiple of 4) -> per-thread const ck.
#define LOAD_A_SWZ(ARR, SET, KS) { _Pragma("unroll") \
  for (int mt = 0; mt < 4; ++mt) \
    SET[mt] = *(const short8*)&ARR[(KS)][mt * 16 + lrow][ck]; }
#define MFMA4(ACC, A, B) { _Pragma("unroll") \
  for (int nt = 0; nt < 4; ++nt) { _Pragma("unroll") \
    for (int mt = 0; mt < 4; ++mt) \
      ACC[mt][nt] = __builtin_amdgcn_mfma_f32_16x16x32_bf16(A[mt], B[nt], ACC[mt][nt], 0, 0, 0); } }

// ---------- g1: x = concat(h[srcS], e)@W1^T ; x-write + col stats ----------
// A-tile staged depth-8; 32KB swizzled LDS (R13). R15: x stores are
// NONTEMPORAL — x is written-once/read-once (by scat) and 328MB/layer, so
// keeping it out of L2 preserves residency for hbf (10MB gather target) and
// w1t. Single variable vs R13.
template <int RELU_E>
__global__ __launch_bounds__(256) void gin_g1(
    const u16* __restrict__ hbf, const u16* __restrict__ ebf,
    const int* __restrict__ srcS, const u16* __restrict__ w1t,
    u16* __restrict__ xout, float* __restrict__ stats) {
  __shared__ u16 sA[8][64][32];  // 32,768 B exactly
  const int tid = threadIdx.x;
  const long e0 = (long)blockIdx.x * 64;
  const int wid = tid >> 6, lane = tid & 63;
  const int lrow = lane & 15, lk = lane >> 4;
  const int ck = (lk ^ (lrow & 3)) * 8;  // swizzled read chunk offset (u16)

  // ---- stage: thread -> (row = tid>>2, chunk c2 = tid&3), one chunk per ks
  {
    const int row = tid >> 2, c2 = tid & 3;
    const int wc = (c2 ^ (row & 3)) * 8;  // swizzled write chunk offset
    const int sr = srcS[e0 + row];
    const u16* hrow = hbf + (size_t)sr * 128 + c2 * 8;
    const u16* erow = ebf + (size_t)(e0 + row) * 128 + c2 * 8;
    short8 t0 = *(const short8*)(hrow + 0);
    short8 t1 = *(const short8*)(hrow + 32);
    short8 t2 = *(const short8*)(hrow + 64);
    short8 t3 = *(const short8*)(hrow + 96);
    short8 t4 = *(const short8*)(erow + 0);
    short8 t5 = *(const short8*)(erow + 32);
    short8 t6 = *(const short8*)(erow + 64);
    short8 t7 = *(const short8*)(erow + 96);
    if (RELU_E) { t4 = relu8(t4); t5 = relu8(t5); t6 = relu8(t6); t7 = relu8(t7); }
    *(short8*)&sA[0][row][wc] = t0;
    *(short8*)&sA[1][row][wc] = t1;
    *(short8*)&sA[2][row][wc] = t2;
    *(short8*)&sA[3][row][wc] = t3;
    *(short8*)&sA[4][row][wc] = t4;
    *(short8*)&sA[5][row][wc] = t5;
    *(short8*)&sA[6][row][wc] = t6;
    *(short8*)&sA[7][row][wc] = t7;
  }

  // ---- B prefetch for ks=0,1 (L2-hot) before the barrier drain
  const u16* wbase = w1t + (size_t)wid * 16384;
  short8 a0[4], a1[4], b0[4], b1[4];
  LOAD_B4(b0, 0)
  LOAD_B4(b1, 1)
  __syncthreads();

  // ---- K-ladder: A from LDS (swizzled), B ping-pong from L2
  f32x4 acc[4][4] = {};
  {
    LOAD_A_SWZ(sA, a0, 0)
    LOAD_A_SWZ(sA, a1, 1)
    MFMA4(acc, a0, b0)
    LOAD_A_SWZ(sA, a0, 2) LOAD_B4(b0, 2)
    MFMA4(acc, a1, b1)
    LOAD_A_SWZ(sA, a1, 3) LOAD_B4(b1, 3)
    MFMA4(acc, a0, b0)
    LOAD_A_SWZ(sA, a0, 4) LOAD_B4(b0, 4)
    MFMA4(acc, a1, b1)
    LOAD_A_SWZ(sA, a1, 5) LOAD_B4(b1, 5)
    MFMA4(acc, a0, b0)
    LOAD_A_SWZ(sA, a0, 6) LOAD_B4(b0, 6)
    MFMA4(acc, a1, b1)
    LOAD_A_SWZ(sA, a1, 7) LOAD_B4(b1, 7)
    MFMA4(acc, a0, b0)
    MFMA4(acc, a1, b1)
  }

  // ---- epilogue: nontemporal x stores + col sum/sumsq partials
  float* statp = stats + (blockIdx.x & 63) * 512;
#pragma unroll
  for (int nt = 0; nt < 4; ++nt) {
    const int col = wid * 64 + nt * 16 + lrow;
    float sm = 0.f, sq = 0.f;
#pragma unroll
    for (int mt = 0; mt < 4; ++mt) {
#pragma unroll
      for (int i = 0; i < 4; ++i) {
        float v = acc[mt][nt][i];
        const long row = e0 + mt * 16 + lk * 4 + i;
        __builtin_nontemporal_store(f2bf(v), xout + (size_t)row * 256 + col);
        sm += v; sq += v * v;
      }
    }
    sm += __shfl_xor(sm, 16); sq += __shfl_xor(sq, 16);
    sm += __shfl_xor(sm, 32); sq += __shfl_xor(sq, 32);
    if (lk == 0) {
      atomicAdd(statp + col, sm);
      atomicAdd(statp + 256 + col, sq);
    }
  }
}

// ---------- BN finalize: a = gamma*rsqrt(var+eps), b = beta - mu*a ----------
__global__ void gin_bnstats(const float* __restrict__ stats,
                            const float* __restrict__ gamma,
                            const float* __restrict__ beta,
                            float* __restrict__ ab) {
  int c = threadIdx.x;  // 256 threads
  float sm = 0.f, sq = 0.f;
  for (int i = 0; i < 64; ++i) {
    sm += stats[i * 512 + c];
    sq += stats[i * 512 + 256 + c];
  }
  const float inv = 1.0f / (float)N_EDGES;
  float mu = sm * inv;
  float var = fmaxf(sq * inv - mu * mu, 0.f);
  float a = gamma[c] * rsqrtf(var + 1e-5f);
  ab[c] = a;
  ab[256 + c] = beta[c] - mu * a;
}

// ---------- scat: Y[dst] += relu(a*x+b)  (R12-proven widened form) ---------
// R15: x loads nontemporal via u64 (plain integer type — uint2 rejected by
// the builtin); stream-once, keep L2 for Y atomics + dstS.
__global__ __launch_bounds__(256) void gin_scat(
    const u16* __restrict__ xin, const float* __restrict__ ab,
    const int* __restrict__ dstS, u16* __restrict__ Y) {
  const int tid = threadIdx.x;
  const long e0 = (long)blockIdx.x * 64;
  const int cq = tid & 63;           // column quad 0..63
  const int qr = tid >> 6;           // row quarter 0..3
  const int col = cq * 4;
  const int r0 = qr * 16;
  const float a0 = ab[col],       a1 = ab[col + 1];
  const float a2 = ab[col + 2],   a3 = ab[col + 3];
  const float b0 = ab[256 + col], b1 = ab[256 + col + 1];
  const float b2 = ab[256 + col + 2], b3 = ab[256 + col + 3];
  float c0 = 0.f, c1 = 0.f, c2 = 0.f, c3 = 0.f;
  int cur = dstS[e0 + r0];
#pragma unroll 4
  for (int r = r0; r < r0 + 16; ++r) {
    u64 u = __builtin_nontemporal_load(
        reinterpret_cast<const u64*>(xin + (size_t)(e0 + r) * 256 + col));
    int d = dstS[e0 + r];
    float y0 = fmaxf(bf2f((u16)(u & 0xFFFFu)) * a0 + b0, 0.f);
    float y1 = fmaxf(bf2f((u16)((u >> 16) & 0xFFFFu)) * a1 + b1, 0.f);
    float y2 = fmaxf(bf2f((u16)((u >> 32) & 0xFFFFu)) * a2 + b2, 0.f);
    float y3 = fmaxf(bf2f((u16)(u >> 48)) * a3 + b3, 0.f);
    if (d != cur) {
      pk_atomic_add_bf16(Y + (size_t)cur * 256 + col, c0, c1);
      pk_atomic_add_bf16(Y + (size_t)cur * 256 + col + 2, c2, c3);
      c0 = c1 = c2 = c3 = 0.f;
      cur = d;
    }
    c0 += y0; c1 += y1; c2 += y2; c3 += y3;
  }
  pk_atomic_add_bf16(Y + (size_t)cur * 256 + col, c0, c1);
  pk_atomic_add_bf16(Y + (size_t)cur * 256 + col + 2, c2, c3);
}

// ---------- nodegemm: h = Y @ W2^T + deg*b2 ; relu+bf16 (l<2) or f32 out ----
template <int LAST>
__global__ __launch_bounds__(256) void gin_nodegemm(
    const u16* __restrict__ Y, const u16* __restrict__ w2t,
    const float* __restrict__ b2, const int* __restrict__ cnt,
    float* __restrict__ outf, u16* __restrict__ hbf) {
  const int tid = threadIdx.x;
  const long n0 = (long)blockIdx.x * 64;
  const int wid = tid >> 6, lane = tid & 63;
  const int lrow = lane & 15, lk = lane >> 4;
  f32x4 acc[4][2] = {};
  const u16* wb2 = w2t + (size_t)wid * 8192;
  for (int ks = 0; ks < 8; ++ks) {
    short8 af[4];
#pragma unroll
    for (int mt = 0; mt < 4; ++mt)
      af[mt] = *(const short8*)(Y + (size_t)(n0 + mt * 16 + lrow) * 256 +
                                ks * 32 + lk * 8);
#pragma unroll
    for (int nt = 0; nt < 2; ++nt) {
      short8 bf = *(const short8*)(wb2 + ((nt * 8 + ks) * 64 + lane) * 8);
#pragma unroll
      for (int mt = 0; mt < 4; ++mt)
        acc[mt][nt] =
            __builtin_amdgcn_mfma_f32_16x16x32_bf16(af[mt], bf, acc[mt][nt], 0, 0, 0);
    }
  }
  float bb[2];
#pragma unroll
  for (int nt = 0; nt < 2; ++nt) bb[nt] = b2[wid * 32 + nt * 16 + lrow];
#pragma unroll
  for (int mt = 0; mt < 4; ++mt) {
#pragma unroll
    for (int i = 0; i < 4; ++i) {
      const long node = n0 + mt * 16 + lk * 4 + i;
      const float dg = (float)cnt[node];
#pragma unroll
      for (int nt = 0; nt < 2; ++nt) {
        const int col = wid * 32 + nt * 16 + lrow;
        float v = acc[mt][nt][i] + dg * bb[nt];
        if (LAST) outf[node * 128 + col] = v;
        else      hbf[node * 128 + col] = f2bf(fmaxf(v, 0.f));
      }
    }
  }
}

// ---------- launch ----------
extern "C" void kernel_launch(void* const* d_in, const int* in_sizes, int n_in,
                              void* d_out, int out_size, void* d_ws, size_t ws_size,
                              hipStream_t stream) {
  const float* h     = (const float*)d_in[0];
  const float* e     = (const float*)d_in[1];
  const float* W1    = (const float*)d_in[2];
  // d_in[3] = b1: cancels exactly in BatchNorm -> unused
  const float* gamma = (const float*)d_in[4];
  const float* beta  = (const float*)d_in[5];
  const float* W2    = (const float*)d_in[6];
  const float* b2    = (const float*)d_in[7];
  const int* src     = (const int*)d_in[8];
  const int* dst     = (const int*)d_in[9];
  float* out = (float*)d_out;

  char* ws = (char*)d_ws;
  u16*   xbuf   = (u16*)(ws);                     // 327,680,000
  u16*   ebfS   = (u16*)(ws + 327680000);         // 163,840,000 (raw, immutable)
  u16*   hbf    = (u16*)(ws + 491520000);         // 10,240,000
  u16*   Y      = (u16*)(ws + 501760000);         // 20,480,000 (bf16 node acc)
  u16*   w1t    = (u16*)(ws + 522240000);         // 393,216
  u16*   w2t    = (u16*)(ws + 522633216);         // 196,608
  float* stats  = (float*)(ws + 522829824);       // 131,072
  float* ab     = (float*)(ws + 522960896);       // 2,048
  int*   cnt    = (int*)(ws + 522962944);         // 160,000
  int*   cursor = (int*)(ws + 523122944);         // 160,000
  int*   srcS   = (int*)(ws + 523282944);         // 2,560,000
  int*   dstS   = (int*)(ws + 525842944);         // 2,560,000
  int*   rank   = (int*)(ws + 528402944);         // 2,560,000 -> 530,962,944
  // total identical to R9-R13's proven workspace bound.

  prep_weights<<<144, 256, 0, stream>>>(W1, W2, w1t, w2t);
  cvt_vec<<<2500, 256, 0, stream>>>(h, hbf, 640000);  // h -> bf16

  // counting sort of edges by dst (static across layers) + sorted bf16 e
  hipMemsetAsync(cnt, 0, 160000, stream);
  hist_dst<<<2500, 256, 0, stream>>>(dst, cnt);
  scan_hist<<<1, 1024, 0, stream>>>(cnt, cursor);
  rank_edges<<<2500, 256, 0, stream>>>(src, dst, cursor, srcS, dstS, rank);
  permute_e<<<10000, 256, 0, stream>>>(e, rank, ebfS);  // raw bf16, sorted order

  const int nblk = N_EDGES / 64;  // 10000
  for (int l = 0; l < 3; ++l) {
    hipMemsetAsync(stats, 0, 64 * 512 * 4, stream);
    if (l == 0)
      gin_g1<0><<<nblk, 256, 0, stream>>>(hbf, ebfS, srcS, w1t, xbuf, stats);
    else
      gin_g1<1><<<nblk, 256, 0, stream>>>(hbf, ebfS, srcS,
                                          w1t + (size_t)l * 65536, xbuf, stats);
    gin_bnstats<<<1, 256, 0, stream>>>(stats, gamma + l * 256, beta + l * 256, ab);
    hipMemsetAsync(Y, 0, 20480000, stream);
    gin_scat<<<nblk, 256, 0, stream>>>(xbuf, ab, dstS, Y);
    if (l < 2)
      gin_nodegemm<0><<<625, 256, 0, stream>>>(Y, w2t + (size_t)l * 32768,
                                               b2 + l * 128, cnt, nullptr, hbf);
    else
      gin_nodegemm<1><<<625, 256, 0, stream>>>(Y, w2t + (size_t)l * 32768,
                                               b2 + l * 128, cnt, out, nullptr);
  }
}

// Round 16
// 1095.208 us; speedup vs baseline: 1.5596x; 1.5596x over previous
//
#include <hip/hip_runtime.h>

typedef unsigned short u16;
typedef unsigned long long u64;
typedef __attribute__((ext_vector_type(8))) short short8;
typedef __attribute__((ext_vector_type(4))) float f32x4;
typedef __attribute__((ext_vector_type(4))) unsigned int u32x4;

#define N_NODES 40000
#define N_EDGES 640000

// ---------- bf16 helpers (RNE) ----------
__device__ __forceinline__ u16 f2bf(float f) {
  unsigned int u = __builtin_bit_cast(unsigned int, f);
  u += 0x7FFFu + ((u >> 16) & 1u);
  return (u16)(u >> 16);
}
__device__ __forceinline__ float bf2f(u16 h) {
  unsigned int u = ((unsigned int)h) << 16;
  return __builtin_bit_cast(float, u);
}
// relu on 8 packed bf16 (sign-mask trick)
__device__ __forceinline__ short8 relu8(short8 s) {
  u32x4 w = __builtin_bit_cast(u32x4, s);
#pragma unroll
  for (int j = 0; j < 4; ++j) {
    unsigned int t = (w[j] >> 15) & 0x10001u;
    w[j] &= ~(t * 0xFFFFu);
  }
  return __builtin_bit_cast(short8, w);
}
// packed bf16 atomic add (gfx950 global_atomic_pk_add_bf16)
__device__ __forceinline__ void pk_atomic_add_bf16(u16* p, float c0, float c1) {
  unsigned int pk = (unsigned int)f2bf(c0) | ((unsigned int)f2bf(c1) << 16);
  asm volatile("global_atomic_pk_add_bf16 %0, %1, off" :: "v"(p), "v"(pk) : "memory");
}

// ---------- prep: W1/W2 f32 -> bf16, permuted into MFMA B-fragment order ----
// B frag for (ntile,ks): lane l holds B[k=ks*32+(l>>4)*8+j][n=ntile*16+(l&15)]
__global__ void prep_weights(const float* __restrict__ W1,
                             const float* __restrict__ W2,
                             u16* __restrict__ w1t, u16* __restrict__ w2t) {
  int gid = blockIdx.x * 256 + threadIdx.x;
  if (gid < 3 * 16 * 8 * 64) {            // W1: 3 layers x 16 ntiles x 8 ks x 64 lanes
    int l = gid >> 13;
    int rem = gid & 8191;
    int ntg = rem >> 9;
    int ks = (rem >> 6) & 7;
    int lane = rem & 63;
    int n = ntg * 16 + (lane & 15);
    int k0 = ks * 32 + (lane >> 4) * 8;
    const float* s = W1 + l * 65536 + n * 256 + k0;
    u16* d = w1t + (size_t)gid * 8;
#pragma unroll
    for (int j = 0; j < 8; ++j) d[j] = f2bf(s[j]);
  } else if (gid < 3 * 16 * 8 * 64 + 3 * 8 * 8 * 64) {  // W2: 8 ntiles
    int g = gid - 3 * 16 * 8 * 64;
    int l = g >> 12;
    int rem = g & 4095;
    int ntg = rem >> 9;
    int ks = (rem >> 6) & 7;
    int lane = rem & 63;
    int n = ntg * 16 + (lane & 15);
    int k0 = ks * 32 + (lane >> 4) * 8;
    const float* s = W2 + l * 32768 + n * 256 + k0;
    u16* d = w2t + (size_t)g * 8;
#pragma unroll
    for (int j = 0; j < 8; ++j) d[j] = f2bf(s[j]);
  }
}

// ---------- f32 -> bf16, vectorized x8 (initial h only) ----------
__global__ void cvt_vec(const float* __restrict__ in, u16* __restrict__ out,
                        int n8) {
  int i = blockIdx.x * 256 + threadIdx.x;
  if (i >= n8) return;
  const float4* p = reinterpret_cast<const float4*>(in) + (size_t)i * 2;
  float4 a = p[0], b = p[1];
  short8 v;
  v[0] = (short)f2bf(a.x); v[1] = (short)f2bf(a.y);
  v[2] = (short)f2bf(a.z); v[3] = (short)f2bf(a.w);
  v[4] = (short)f2bf(b.x); v[5] = (short)f2bf(b.y);
  v[6] = (short)f2bf(b.z); v[7] = (short)f2bf(b.w);
  *reinterpret_cast<short8*>(out + (size_t)i * 8) = v;
}

// ---------- counting sort of edges by dst ----------
__global__ void hist_dst(const int* __restrict__ dst, int* __restrict__ cnt) {
  int e = blockIdx.x * 256 + threadIdx.x;
  if (e < N_EDGES) atomicAdd(&cnt[dst[e]], 1);
}

__global__ void scan_hist(const int* __restrict__ cnt, int* __restrict__ cursor) {
  __shared__ int ls[1024];
  const int tid = threadIdx.x;  // 1024 threads, 40 nodes each
  const int b = tid * 40;
  const int lim = (b < N_NODES) ? ((N_NODES - b < 40) ? (N_NODES - b) : 40) : 0;
  int s = 0;
  for (int j = 0; j < lim; ++j) s += cnt[b + j];
  ls[tid] = s;
  __syncthreads();
  for (int off = 1; off < 1024; off <<= 1) {
    int v = (tid >= off) ? ls[tid - off] : 0;
    __syncthreads();
    ls[tid] += v;
    __syncthreads();
  }
  int run = (tid == 0) ? 0 : ls[tid - 1];
  for (int j = 0; j < lim; ++j) {
    cursor[b + j] = run;
    run += cnt[b + j];
  }
}

__global__ void rank_edges(const int* __restrict__ src, const int* __restrict__ dst,
                           int* __restrict__ cursor, int* __restrict__ srcS,
                           int* __restrict__ dstS, int* __restrict__ rank) {
  int e = blockIdx.x * 256 + threadIdx.x;
  if (e >= N_EDGES) return;
  int d = dst[e];
  int r = atomicAdd(&cursor[d], 1);
  rank[e] = r;
  srcS[r] = src[e];
  dstS[r] = d;
}

// ---------- permute e into sorted slot order, f32 -> bf16 (raw, no relu) ----
__global__ void permute_e(const float* __restrict__ e, const int* __restrict__ rank,
                          u16* __restrict__ ebfS) {
  int t = blockIdx.x * 256 + threadIdx.x;
  int row = t >> 2;
  int part = t & 3;  // 32-float chunk of the row
  if (row >= N_EDGES) return;
  const float4* p = reinterpret_cast<const float4*>(e + (size_t)row * 128 + part * 32);
  u16* dp = ebfS + (size_t)rank[row] * 128 + part * 32;
#pragma unroll
  for (int j = 0; j < 4; ++j) {
    float4 a = p[j * 2], b = p[j * 2 + 1];
    short8 v;
    v[0] = (short)f2bf(a.x); v[1] = (short)f2bf(a.y);
    v[2] = (short)f2bf(a.z); v[3] = (short)f2bf(a.w);
    v[4] = (short)f2bf(b.x); v[5] = (short)f2bf(b.y);
    v[6] = (short)f2bf(b.z); v[7] = (short)f2bf(b.w);
    *(short8*)(dp + j * 8) = v;
  }
}

// ---------- ladder building blocks ----------
#define LOAD_B4(SET, KS) { _Pragma("unroll") \
  for (int nt = 0; nt < 4; ++nt) \
    SET[nt] = *(const short8*)(wbase + ((nt * 8 + (KS)) * 64 + lane) * 8); }
// A read from swizzled LDS: logical chunk lk lives at physical chunk
// lk ^ (row&3); row&3 == lrow&3 (mt*16 multiple of 4) -> per-thread const ck.
#define LOAD_A_SWZ(ARR, SET, KS) { _Pragma("unroll") \
  for (int mt = 0; mt < 4; ++mt) \
    SET[mt] = *(const short8*)&ARR[(KS)][mt * 16 + lrow][ck]; }
#define MFMA4(ACC, A, B) { _Pragma("unroll") \
  for (int nt = 0; nt < 4; ++nt) { _Pragma("unroll") \
    for (int mt = 0; mt < 4; ++mt) \
      ACC[mt][nt] = __builtin_amdgcn_mfma_f32_16x16x32_bf16(A[mt], B[nt], ACC[mt][nt], 0, 0, 0); } }

// ---------- g1: x = concat(h[srcS], e)@W1^T ; x-write + col stats ----------
// A-tile staged depth-8; 32KB swizzled LDS (R13). R16: x stores reverted to
// PLAIN stores (R15's nontemporal 2B stores bypassed L2 write-combining ->
// 525MB WRITE_SIZE, +220us/dispatch). g1 is byte-identical to R13.
template <int RELU_E>
__global__ __launch_bounds__(256) void gin_g1(
    const u16* __restrict__ hbf, const u16* __restrict__ ebf,
    const int* __restrict__ srcS, const u16* __restrict__ w1t,
    u16* __restrict__ xout, float* __restrict__ stats) {
  __shared__ u16 sA[8][64][32];  // 32,768 B exactly
  const int tid = threadIdx.x;
  const long e0 = (long)blockIdx.x * 64;
  const int wid = tid >> 6, lane = tid & 63;
  const int lrow = lane & 15, lk = lane >> 4;
  const int ck = (lk ^ (lrow & 3)) * 8;  // swizzled read chunk offset (u16)

  // ---- stage: thread -> (row = tid>>2, chunk c2 = tid&3), one chunk per ks
  {
    const int row = tid >> 2, c2 = tid & 3;
    const int wc = (c2 ^ (row & 3)) * 8;  // swizzled write chunk offset
    const int sr = srcS[e0 + row];
    const u16* hrow = hbf + (size_t)sr * 128 + c2 * 8;
    const u16* erow = ebf + (size_t)(e0 + row) * 128 + c2 * 8;
    short8 t0 = *(const short8*)(hrow + 0);
    short8 t1 = *(const short8*)(hrow + 32);
    short8 t2 = *(const short8*)(hrow + 64);
    short8 t3 = *(const short8*)(hrow + 96);
    short8 t4 = *(const short8*)(erow + 0);
    short8 t5 = *(const short8*)(erow + 32);
    short8 t6 = *(const short8*)(erow + 64);
    short8 t7 = *(const short8*)(erow + 96);
    if (RELU_E) { t4 = relu8(t4); t5 = relu8(t5); t6 = relu8(t6); t7 = relu8(t7); }
    *(short8*)&sA[0][row][wc] = t0;
    *(short8*)&sA[1][row][wc] = t1;
    *(short8*)&sA[2][row][wc] = t2;
    *(short8*)&sA[3][row][wc] = t3;
    *(short8*)&sA[4][row][wc] = t4;
    *(short8*)&sA[5][row][wc] = t5;
    *(short8*)&sA[6][row][wc] = t6;
    *(short8*)&sA[7][row][wc] = t7;
  }

  // ---- B prefetch for ks=0,1 (L2-hot) before the barrier drain
  const u16* wbase = w1t + (size_t)wid * 16384;
  short8 a0[4], a1[4], b0[4], b1[4];
  LOAD_B4(b0, 0)
  LOAD_B4(b1, 1)
  __syncthreads();

  // ---- K-ladder: A from LDS (swizzled), B ping-pong from L2
  f32x4 acc[4][4] = {};
  {
    LOAD_A_SWZ(sA, a0, 0)
    LOAD_A_SWZ(sA, a1, 1)
    MFMA4(acc, a0, b0)
    LOAD_A_SWZ(sA, a0, 2) LOAD_B4(b0, 2)
    MFMA4(acc, a1, b1)
    LOAD_A_SWZ(sA, a1, 3) LOAD_B4(b1, 3)
    MFMA4(acc, a0, b0)
    LOAD_A_SWZ(sA, a0, 4) LOAD_B4(b0, 4)
    MFMA4(acc, a1, b1)
    LOAD_A_SWZ(sA, a1, 5) LOAD_B4(b1, 5)
    MFMA4(acc, a0, b0)
    LOAD_A_SWZ(sA, a0, 6) LOAD_B4(b0, 6)
    MFMA4(acc, a1, b1)
    LOAD_A_SWZ(sA, a1, 7) LOAD_B4(b1, 7)
    MFMA4(acc, a0, b0)
    MFMA4(acc, a1, b1)
  }

  // ---- epilogue: plain x stores (L2 write-combined) + col sum/sumsq
  float* statp = stats + (blockIdx.x & 63) * 512;
#pragma unroll
  for (int nt = 0; nt < 4; ++nt) {
    const int col = wid * 64 + nt * 16 + lrow;
    float sm = 0.f, sq = 0.f;
#pragma unroll
    for (int mt = 0; mt < 4; ++mt) {
#pragma unroll
      for (int i = 0; i < 4; ++i) {
        float v = acc[mt][nt][i];
        const long row = e0 + mt * 16 + lk * 4 + i;
        xout[(size_t)row * 256 + col] = f2bf(v);
        sm += v; sq += v * v;
      }
    }
    sm += __shfl_xor(sm, 16); sq += __shfl_xor(sq, 16);
    sm += __shfl_xor(sm, 32); sq += __shfl_xor(sq, 32);
    if (lk == 0) {
      atomicAdd(statp + col, sm);
      atomicAdd(statp + 256 + col, sq);
    }
  }
}

// ---------- BN finalize: a = gamma*rsqrt(var+eps), b = beta - mu*a ----------
__global__ void gin_bnstats(const float* __restrict__ stats,
                            const float* __restrict__ gamma,
                            const float* __restrict__ beta,
                            float* __restrict__ ab) {
  int c = threadIdx.x;  // 256 threads
  float sm = 0.f, sq = 0.f;
  for (int i = 0; i < 64; ++i) {
    sm += stats[i * 512 + c];
    sq += stats[i * 512 + 256 + c];
  }
  const float inv = 1.0f / (float)N_EDGES;
  float mu = sm * inv;
  float var = fmaxf(sq * inv - mu * mu, 0.f);
  float a = gamma[c] * rsqrtf(var + 1e-5f);
  ab[c] = a;
  ab[256 + c] = beta[c] - mu * a;
}

// ---------- scat: Y[dst] += relu(a*x+b)  (R12-proven widened form) ---------
// R16: keeps the u64 nontemporal x load (read-once stream; no write-side
// amplification risk) — the single variable vs R13.
__global__ __launch_bounds__(256) void gin_scat(
    const u16* __restrict__ xin, const float* __restrict__ ab,
    const int* __restrict__ dstS, u16* __restrict__ Y) {
  const int tid = threadIdx.x;
  const long e0 = (long)blockIdx.x * 64;
  const int cq = tid & 63;           // column quad 0..63
  const int qr = tid >> 6;           // row quarter 0..3
  const int col = cq * 4;
  const int r0 = qr * 16;
  const float a0 = ab[col],       a1 = ab[col + 1];
  const float a2 = ab[col + 2],   a3 = ab[col + 3];
  const float b0 = ab[256 + col], b1 = ab[256 + col + 1];
  const float b2 = ab[256 + col + 2], b3 = ab[256 + col + 3];
  float c0 = 0.f, c1 = 0.f, c2 = 0.f, c3 = 0.f;
  int cur = dstS[e0 + r0];
#pragma unroll 4
  for (int r = r0; r < r0 + 16; ++r) {
    u64 u = __builtin_nontemporal_load(
        reinterpret_cast<const u64*>(xin + (size_t)(e0 + r) * 256 + col));
    int d = dstS[e0 + r];
    float y0 = fmaxf(bf2f((u16)(u & 0xFFFFu)) * a0 + b0, 0.f);
    float y1 = fmaxf(bf2f((u16)((u >> 16) & 0xFFFFu)) * a1 + b1, 0.f);
    float y2 = fmaxf(bf2f((u16)((u >> 32) & 0xFFFFu)) * a2 + b2, 0.f);
    float y3 = fmaxf(bf2f((u16)(u >> 48)) * a3 + b3, 0.f);
    if (d != cur) {
      pk_atomic_add_bf16(Y + (size_t)cur * 256 + col, c0, c1);
      pk_atomic_add_bf16(Y + (size_t)cur * 256 + col + 2, c2, c3);
      c0 = c1 = c2 = c3 = 0.f;
      cur = d;
    }
    c0 += y0; c1 += y1; c2 += y2; c3 += y3;
  }
  pk_atomic_add_bf16(Y + (size_t)cur * 256 + col, c0, c1);
  pk_atomic_add_bf16(Y + (size_t)cur * 256 + col + 2, c2, c3);
}

// ---------- nodegemm: h = Y @ W2^T + deg*b2 ; relu+bf16 (l<2) or f32 out ----
template <int LAST>
__global__ __launch_bounds__(256) void gin_nodegemm(
    const u16* __restrict__ Y, const u16* __restrict__ w2t,
    const float* __restrict__ b2, const int* __restrict__ cnt,
    float* __restrict__ outf, u16* __restrict__ hbf) {
  const int tid = threadIdx.x;
  const long n0 = (long)blockIdx.x * 64;
  const int wid = tid >> 6, lane = tid & 63;
  const int lrow = lane & 15, lk = lane >> 4;
  f32x4 acc[4][2] = {};
  const u16* wb2 = w2t + (size_t)wid * 8192;
  for (int ks = 0; ks < 8; ++ks) {
    short8 af[4];
#pragma unroll
    for (int mt = 0; mt < 4; ++mt)
      af[mt] = *(const short8*)(Y + (size_t)(n0 + mt * 16 + lrow) * 256 +
                                ks * 32 + lk * 8);
#pragma unroll
    for (int nt = 0; nt < 2; ++nt) {
      short8 bf = *(const short8*)(wb2 + ((nt * 8 + ks) * 64 + lane) * 8);
#pragma unroll
      for (int mt = 0; mt < 4; ++mt)
        acc[mt][nt] =
            __builtin_amdgcn_mfma_f32_16x16x32_bf16(af[mt], bf, acc[mt][nt], 0, 0, 0);
    }
  }
  float bb[2];
#pragma unroll
  for (int nt = 0; nt < 2; ++nt) bb[nt] = b2[wid * 32 + nt * 16 + lrow];
#pragma unroll
  for (int mt = 0; mt < 4; ++mt) {
#pragma unroll
    for (int i = 0; i < 4; ++i) {
      const long node = n0 + mt * 16 + lk * 4 + i;
      const float dg = (float)cnt[node];
#pragma unroll
      for (int nt = 0; nt < 2; ++nt) {
        const int col = wid * 32 + nt * 16 + lrow;
        float v = acc[mt][nt][i] + dg * bb[nt];
        if (LAST) outf[node * 128 + col] = v;
        else      hbf[node * 128 + col] = f2bf(fmaxf(v, 0.f));
      }
    }
  }
}

// ---------- launch ----------
extern "C" void kernel_launch(void* const* d_in, const int* in_sizes, int n_in,
                              void* d_out, int out_size, void* d_ws, size_t ws_size,
                              hipStream_t stream) {
  const float* h     = (const float*)d_in[0];
  const float* e     = (const float*)d_in[1];
  const float* W1    = (const float*)d_in[2];
  // d_in[3] = b1: cancels exactly in BatchNorm -> unused
  const float* gamma = (const float*)d_in[4];
  const float* beta  = (const float*)d_in[5];
  const float* W2    = (const float*)d_in[6];
  const float* b2    = (const float*)d_in[7];
  const int* src     = (const int*)d_in[8];
  const int* dst     = (const int*)d_in[9];
  float* out = (float*)d_out;

  char* ws = (char*)d_ws;
  u16*   xbuf   = (u16*)(ws);                     // 327,680,000
  u16*   ebfS   = (u16*)(ws + 327680000);         // 163,840,000 (raw, immutable)
  u16*   hbf    = (u16*)(ws + 491520000);         // 10,240,000
  u16*   Y      = (u16*)(ws + 501760000);         // 20,480,000 (bf16 node acc)
  u16*   w1t    = (u16*)(ws + 522240000);         // 393,216
  u16*   w2t    = (u16*)(ws + 522633216);         // 196,608
  float* stats  = (float*)(ws + 522829824);       // 131,072
  float* ab     = (float*)(ws + 522960896);       // 2,048
  int*   cnt    = (int*)(ws + 522962944);         // 160,000
  int*   cursor = (int*)(ws + 523122944);         // 160,000
  int*   srcS   = (int*)(ws + 523282944);         // 2,560,000
  int*   dstS   = (int*)(ws + 525842944);         // 2,560,000
  int*   rank   = (int*)(ws + 528402944);         // 2,560,000 -> 530,962,944
  // total identical to R9-R13's proven workspace bound.

  prep_weights<<<144, 256, 0, stream>>>(W1, W2, w1t, w2t);
  cvt_vec<<<2500, 256, 0, stream>>>(h, hbf, 640000);  // h -> bf16

  // counting sort of edges by dst (static across layers) + sorted bf16 e
  hipMemsetAsync(cnt, 0, 160000, stream);
  hist_dst<<<2500, 256, 0, stream>>>(dst, cnt);
  scan_hist<<<1, 1024, 0, stream>>>(cnt, cursor);
  rank_edges<<<2500, 256, 0, stream>>>(src, dst, cursor, srcS, dstS, rank);
  permute_e<<<10000, 256, 0, stream>>>(e, rank, ebfS);  // raw bf16, sorted order

  const int nblk = N_EDGES / 64;  // 10000
  for (int l = 0; l < 3; ++l) {
    hipMemsetAsync(stats, 0, 64 * 512 * 4, stream);
    if (l == 0)
      gin_g1<0><<<nblk, 256, 0, stream>>>(hbf, ebfS, srcS, w1t, xbuf, stats);
    else
      gin_g1<1><<<nblk, 256, 0, stream>>>(hbf, ebfS, srcS,
                                          w1t + (size_t)l * 65536, xbuf, stats);
    gin_bnstats<<<1, 256, 0, stream>>>(stats, gamma + l * 256, beta + l * 256, ab);
    hipMemsetAsync(Y, 0, 20480000, stream);
    gin_scat<<<nblk, 256, 0, stream>>>(xbuf, ab, dstS, Y);
    if (l < 2)
      gin_nodegemm<0><<<625, 256, 0, stream>>>(Y, w2t + (size_t)l * 32768,
                                               b2 + l * 128, cnt, nullptr, hbf);
    else
      gin_nodegemm<1><<<625, 256, 0, stream>>>(Y, w2t + (size_t)l * 32768,
                                               b2 + l * 128, cnt, out, nullptr);
  }
}